// Round 1
// baseline (763.661 us; speedup 1.0000x reference)
//
#include <hip/hip_runtime.h>
#include <math.h>

#define B_ 16
#define D_ 512
#define N_ 4096   // H*W = 64*64
#define K_ 64

// ---------------------------------------------------------------------------
// K1: logits + softmax over clusters. One thread per pixel n, 64 fp32 accs.
// conv_w accessed with wave-uniform indices -> scalar loads (s_load_dwordx4).
// ---------------------------------------------------------------------------
__global__ __launch_bounds__(256) void k_softmax(
    const float* __restrict__ x, const float* __restrict__ conv_w,
    const float* __restrict__ conv_b, float* __restrict__ w_out)
{
    const int b    = blockIdx.x >> 4;     // 16 tiles of 256 pixels per batch
    const int tile = blockIdx.x & 15;
    const int n    = tile * 256 + threadIdx.x;
    const float* xb = x + (size_t)b * D_ * N_ + n;

    float acc[K_];
    #pragma unroll
    for (int k = 0; k < K_; ++k) acc[k] = conv_b[k];

    const float4* cw4 = (const float4*)conv_w;   // (K, D/4) float4s, uniform
    for (int d4 = 0; d4 < D_ / 4; ++d4) {
        const float x0 = xb[(4 * d4 + 0) * N_];
        const float x1 = xb[(4 * d4 + 1) * N_];
        const float x2 = xb[(4 * d4 + 2) * N_];
        const float x3 = xb[(4 * d4 + 3) * N_];
        #pragma unroll
        for (int k = 0; k < K_; ++k) {
            const float4 wv = cw4[k * (D_ / 4) + d4];  // uniform -> s_load
            float a = acc[k];
            a = fmaf(wv.x, x0, a);
            a = fmaf(wv.y, x1, a);
            a = fmaf(wv.z, x2, a);
            a = fmaf(wv.w, x3, a);
            acc[k] = a;
        }
    }

    // stable softmax over k (all in registers)
    float m = acc[0];
    #pragma unroll
    for (int k = 1; k < K_; ++k) m = fmaxf(m, acc[k]);
    float s = 0.f;
    #pragma unroll
    for (int k = 0; k < K_; ++k) { float e = __expf(acc[k] - m); acc[k] = e; s += e; }
    const float inv = 1.0f / s;

    float* wo = w_out + (size_t)b * K_ * N_ + n;
    #pragma unroll
    for (int k = 0; k < K_; ++k) wo[k * N_] = acc[k] * inv;
}

// ---------------------------------------------------------------------------
// K2: vlad[b,k,d] += sum_n w[b,k,n] * x[b,d,n].  Per-b GEMM, both operands
// contiguous along n. Tiles: K=64 x D=64 per block, n-chunk 1024 (4-way
// split with atomicAdd). LDS staged transposed [nn][row], stride 68 pad.
// ---------------------------------------------------------------------------
__global__ __launch_bounds__(256) void k_wx(
    const float* __restrict__ x, const float* __restrict__ w,
    float* __restrict__ vlad)
{
    const int ns = blockIdx.x & 3;          // n split (4 x 1024)
    const int dt = (blockIdx.x >> 2) & 7;   // d tile (8 x 64)
    const int b  = blockIdx.x >> 5;

    const float* wb = w + (size_t)b * K_ * N_;
    const float* xb = x + (size_t)b * D_ * N_ + (size_t)dt * 64 * N_;

    __shared__ float ls_w[32][68];  // [nn][k], stride 68 floats (16B aligned)
    __shared__ float ls_x[32][68];  // [nn][d]

    const int tid = threadIdx.x;
    const int tx = tid & 15;        // k group: k = tx*4 + i
    const int ty = tid >> 4;        // d group: d = ty*4 + j

    float acc[4][4];
    #pragma unroll
    for (int i = 0; i < 4; ++i)
        #pragma unroll
        for (int j = 0; j < 4; ++j) acc[i][j] = 0.f;

    const int n0base = ns * 1024;
    for (int n0 = n0base; n0 < n0base + 1024; n0 += 32) {
        // stage 64 rows x 32 n of both w and x, transposed into LDS
        #pragma unroll
        for (int p = 0; p < 8; ++p) {
            const int idx = p * 256 + tid;
            const int row = idx >> 5;     // 0..63
            const int nn  = idx & 31;
            ls_w[nn][row] = wb[(size_t)row * N_ + n0 + nn];
            ls_x[nn][row] = xb[(size_t)row * N_ + n0 + nn];
        }
        __syncthreads();
        #pragma unroll
        for (int nn = 0; nn < 32; ++nn) {
            const float4 wk = *(const float4*)&ls_w[nn][tx * 4];
            const float4 xd = *(const float4*)&ls_x[nn][ty * 4];
            acc[0][0] = fmaf(wk.x, xd.x, acc[0][0]);
            acc[0][1] = fmaf(wk.x, xd.y, acc[0][1]);
            acc[0][2] = fmaf(wk.x, xd.z, acc[0][2]);
            acc[0][3] = fmaf(wk.x, xd.w, acc[0][3]);
            acc[1][0] = fmaf(wk.y, xd.x, acc[1][0]);
            acc[1][1] = fmaf(wk.y, xd.y, acc[1][1]);
            acc[1][2] = fmaf(wk.y, xd.z, acc[1][2]);
            acc[1][3] = fmaf(wk.y, xd.w, acc[1][3]);
            acc[2][0] = fmaf(wk.z, xd.x, acc[2][0]);
            acc[2][1] = fmaf(wk.z, xd.y, acc[2][1]);
            acc[2][2] = fmaf(wk.z, xd.z, acc[2][2]);
            acc[2][3] = fmaf(wk.z, xd.w, acc[2][3]);
            acc[3][0] = fmaf(wk.w, xd.x, acc[3][0]);
            acc[3][1] = fmaf(wk.w, xd.y, acc[3][1]);
            acc[3][2] = fmaf(wk.w, xd.z, acc[3][2]);
            acc[3][3] = fmaf(wk.w, xd.w, acc[3][3]);
        }
        __syncthreads();
    }

    #pragma unroll
    for (int i = 0; i < 4; ++i) {
        const int k = tx * 4 + i;
        #pragma unroll
        for (int j = 0; j < 4; ++j) {
            const int d = dt * 64 + ty * 4 + j;
            atomicAdd(&vlad[((size_t)b * K_ + k) * D_ + d], acc[i][j]);
        }
    }
}

// ---------------------------------------------------------------------------
// K3: per (b,k): wsum = sum_n w; v = vlad - wsum*c; intra L2-norm; global
// norm is exactly sqrt(K)=8 since rows are unit-normalized -> fold /8 in.
// ---------------------------------------------------------------------------
__global__ __launch_bounds__(256) void k_norm(
    const float* __restrict__ w, const float* __restrict__ vlad,
    const float* __restrict__ centers, float* __restrict__ out)
{
    const int b = blockIdx.x >> 6;
    const int k = blockIdx.x & 63;
    const int tid = threadIdx.x;

    const float* wr = w + ((size_t)b * K_ + k) * N_;
    float s = 0.f;
    #pragma unroll
    for (int i = 0; i < N_ / 256; ++i) s += wr[i * 256 + tid];

    __shared__ float red1[4];
    #pragma unroll
    for (int off = 32; off > 0; off >>= 1) s += __shfl_down(s, off, 64);
    if ((tid & 63) == 0) red1[tid >> 6] = s;
    __syncthreads();
    const float wsum = red1[0] + red1[1] + red1[2] + red1[3];

    const float* vr = vlad + ((size_t)b * K_ + k) * D_;
    const float* cr = centers + k * D_;
    const float v0 = vr[tid]       - wsum * cr[tid];
    const float v1 = vr[tid + 256] - wsum * cr[tid + 256];

    float ss = v0 * v0 + v1 * v1;
    __shared__ float red2[4];
    #pragma unroll
    for (int off = 32; off > 0; off >>= 1) ss += __shfl_down(ss, off, 64);
    if ((tid & 63) == 0) red2[tid >> 6] = ss;
    __syncthreads();
    const float nrm = sqrtf(red2[0] + red2[1] + red2[2] + red2[3]);
    const float scale = 1.0f / (8.0f * fmaxf(nrm, 1e-12f));

    float* outr = out + ((size_t)b * K_ + k) * D_;
    outr[tid]       = v0 * scale;
    outr[tid + 256] = v1 * scale;
}

extern "C" void kernel_launch(void* const* d_in, const int* in_sizes, int n_in,
                              void* d_out, int out_size, void* d_ws, size_t ws_size,
                              hipStream_t stream) {
    const float* x       = (const float*)d_in[0];
    const float* conv_w  = (const float*)d_in[1];
    const float* conv_b  = (const float*)d_in[2];
    const float* centers = (const float*)d_in[3];
    float* out = (float*)d_out;

    char* wsb = (char*)d_ws;
    float* vlad = (float*)wsb;                                  // B*K*D = 2 MiB
    float* wbuf = (float*)(wsb + (size_t)B_ * K_ * D_ * sizeof(float)); // B*K*N = 16 MiB

    hipMemsetAsync(vlad, 0, (size_t)B_ * K_ * D_ * sizeof(float), stream);

    k_softmax<<<B_ * (N_ / 256), 256, 0, stream>>>(x, conv_w, conv_b, wbuf);
    k_wx<<<B_ * 8 * 4, 256, 0, stream>>>(x, wbuf, vlad);
    k_norm<<<B_ * K_, 256, 0, stream>>>(wbuf, vlad, centers, out);
}

// Round 2
// 335.637 us; speedup vs baseline: 2.2753x; 2.2753x over previous
//
#include <hip/hip_runtime.h>
#include <math.h>

#define B_ 16
#define D_ 512
#define N_ 4096   // H*W = 64*64
#define K_ 64

// ---------------------------------------------------------------------------
// K1: logits GEMM (64k x 128n per block, D=512 reduction) + per-pixel softmax.
// Register tile 4k x 8n (32 accs) -- round-1 version spilled acc[64] to
// scratch (VGPR_Count=44, VALUBusy 18%). LDS-staged, float4 reads.
// ---------------------------------------------------------------------------
__global__ __launch_bounds__(256) void k_softmax(
    const float* __restrict__ x, const float* __restrict__ conv_w,
    const float* __restrict__ conv_b, float* __restrict__ w_out)
{
    const int b  = blockIdx.x >> 5;   // 32 n-tiles of 128 per batch
    const int nt = blockIdx.x & 31;
    const int n0 = nt * 128;

    __shared__ float ls_x[32][132];     // [dd][n]  (pad 4: 16B-aligned rows)
    __shared__ float ls_cw[32][68];     // [dd][k]
    __shared__ float ls_logit[64][128]; // [k][n]

    const int tid = threadIdx.x;
    const int tx = tid & 15;   // n group: n = tx*4+j  and  64+tx*4+j
    const int ty = tid >> 4;   // k group: k = ty*4+i

    float acc[4][8];
    #pragma unroll
    for (int i = 0; i < 4; ++i)
        #pragma unroll
        for (int j = 0; j < 8; ++j) acc[i][j] = 0.f;

    const float* xb = x + (size_t)b * D_ * N_ + n0;

    for (int d0 = 0; d0 < D_; d0 += 32) {
        // stage x tile: 32 dd x 128 n = 1024 float4s, 4 per thread, coalesced
        #pragma unroll
        for (int p = 0; p < 4; ++p) {
            const int idx = p * 256 + tid;
            const int dd  = idx >> 5;
            const int nn4 = idx & 31;
            *(float4*)&ls_x[dd][nn4 * 4] =
                *(const float4*)&xb[(size_t)(d0 + dd) * N_ + nn4 * 4];
        }
        // stage conv_w tile transposed: 64 k x 32 dd, scalar, coalesced on d
        #pragma unroll
        for (int p = 0; p < 8; ++p) {
            const int idx = p * 256 + tid;
            const int k  = idx >> 5;
            const int dd = idx & 31;
            ls_cw[dd][k] = conv_w[k * D_ + d0 + dd];
        }
        __syncthreads();
        #pragma unroll
        for (int dd = 0; dd < 32; ++dd) {
            const float4 cw = *(const float4*)&ls_cw[dd][ty * 4];
            const float4 x0 = *(const float4*)&ls_x[dd][tx * 4];
            const float4 x1 = *(const float4*)&ls_x[dd][64 + tx * 4];
            const float cwv[4] = {cw.x, cw.y, cw.z, cw.w};
            const float xv[8]  = {x0.x, x0.y, x0.z, x0.w, x1.x, x1.y, x1.z, x1.w};
            #pragma unroll
            for (int i = 0; i < 4; ++i)
                #pragma unroll
                for (int j = 0; j < 8; ++j)
                    acc[i][j] = fmaf(cwv[i], xv[j], acc[i][j]);
        }
        __syncthreads();
    }

    // bias + scatter logits to LDS
    #pragma unroll
    for (int i = 0; i < 4; ++i) {
        const float bias = conv_b[ty * 4 + i];
        #pragma unroll
        for (int j = 0; j < 8; ++j) {
            const int n = (j < 4) ? (tx * 4 + j) : (64 + tx * 4 + (j - 4));
            ls_logit[ty * 4 + i][n] = acc[i][j] + bias;
        }
    }
    __syncthreads();

    // per-pixel softmax over k, 128 threads each own one column n
    if (tid < 128) {
        const int n = tid;
        float m = -INFINITY;
        #pragma unroll
        for (int k = 0; k < K_; ++k) m = fmaxf(m, ls_logit[k][n]);
        float s = 0.f;
        #pragma unroll
        for (int k = 0; k < K_; ++k) {
            const float e = __expf(ls_logit[k][n] - m);
            ls_logit[k][n] = e;
            s += e;
        }
        const float inv = 1.0f / s;
        float* wo = w_out + (size_t)b * K_ * N_ + n0 + n;
        #pragma unroll
        for (int k = 0; k < K_; ++k) wo[(size_t)k * N_] = ls_logit[k][n] * inv;
    }
}

// ---------------------------------------------------------------------------
// K2: vlad[b,k,d] += sum_n w[b,k,n] * x[b,d,n].  (unchanged from round 1)
// ---------------------------------------------------------------------------
__global__ __launch_bounds__(256) void k_wx(
    const float* __restrict__ x, const float* __restrict__ w,
    float* __restrict__ vlad)
{
    const int ns = blockIdx.x & 3;          // n split (4 x 1024)
    const int dt = (blockIdx.x >> 2) & 7;   // d tile (8 x 64)
    const int b  = blockIdx.x >> 5;

    const float* wb = w + (size_t)b * K_ * N_;
    const float* xb = x + (size_t)b * D_ * N_ + (size_t)dt * 64 * N_;

    __shared__ float ls_w[32][68];  // [nn][k]
    __shared__ float ls_x[32][68];  // [nn][d]

    const int tid = threadIdx.x;
    const int tx = tid & 15;        // k group: k = tx*4 + i
    const int ty = tid >> 4;        // d group: d = ty*4 + j

    float acc[4][4];
    #pragma unroll
    for (int i = 0; i < 4; ++i)
        #pragma unroll
        for (int j = 0; j < 4; ++j) acc[i][j] = 0.f;

    const int n0base = ns * 1024;
    for (int n0 = n0base; n0 < n0base + 1024; n0 += 32) {
        #pragma unroll
        for (int p = 0; p < 8; ++p) {
            const int idx = p * 256 + tid;
            const int row = idx >> 5;     // 0..63
            const int nn  = idx & 31;
            ls_w[nn][row] = wb[(size_t)row * N_ + n0 + nn];
            ls_x[nn][row] = xb[(size_t)row * N_ + n0 + nn];
        }
        __syncthreads();
        #pragma unroll
        for (int nn = 0; nn < 32; ++nn) {
            const float4 wk = *(const float4*)&ls_w[nn][tx * 4];
            const float4 xd = *(const float4*)&ls_x[nn][ty * 4];
            const float wv[4] = {wk.x, wk.y, wk.z, wk.w};
            const float xv[4] = {xd.x, xd.y, xd.z, xd.w};
            #pragma unroll
            for (int i = 0; i < 4; ++i)
                #pragma unroll
                for (int j = 0; j < 4; ++j)
                    acc[i][j] = fmaf(wv[i], xv[j], acc[i][j]);
        }
        __syncthreads();
    }

    #pragma unroll
    for (int i = 0; i < 4; ++i) {
        const int k = tx * 4 + i;
        #pragma unroll
        for (int j = 0; j < 4; ++j) {
            const int d = dt * 64 + ty * 4 + j;
            atomicAdd(&vlad[((size_t)b * K_ + k) * D_ + d], acc[i][j]);
        }
    }
}

// ---------------------------------------------------------------------------
// K3: residual subtract + intra L2-norm + global norm (= /8).  (unchanged)
// ---------------------------------------------------------------------------
__global__ __launch_bounds__(256) void k_norm(
    const float* __restrict__ w, const float* __restrict__ vlad,
    const float* __restrict__ centers, float* __restrict__ out)
{
    const int b = blockIdx.x >> 6;
    const int k = blockIdx.x & 63;
    const int tid = threadIdx.x;

    const float* wr = w + ((size_t)b * K_ + k) * N_;
    float s = 0.f;
    #pragma unroll
    for (int i = 0; i < N_ / 256; ++i) s += wr[i * 256 + tid];

    __shared__ float red1[4];
    #pragma unroll
    for (int off = 32; off > 0; off >>= 1) s += __shfl_down(s, off, 64);
    if ((tid & 63) == 0) red1[tid >> 6] = s;
    __syncthreads();
    const float wsum = red1[0] + red1[1] + red1[2] + red1[3];

    const float* vr = vlad + ((size_t)b * K_ + k) * D_;
    const float* cr = centers + k * D_;
    const float v0 = vr[tid]       - wsum * cr[tid];
    const float v1 = vr[tid + 256] - wsum * cr[tid + 256];

    float ss = v0 * v0 + v1 * v1;
    __shared__ float red2[4];
    #pragma unroll
    for (int off = 32; off > 0; off >>= 1) ss += __shfl_down(ss, off, 64);
    if ((tid & 63) == 0) red2[tid >> 6] = ss;
    __syncthreads();
    const float nrm = sqrtf(red2[0] + red2[1] + red2[2] + red2[3]);
    const float scale = 1.0f / (8.0f * fmaxf(nrm, 1e-12f));

    float* outr = out + ((size_t)b * K_ + k) * D_;
    outr[tid]       = v0 * scale;
    outr[tid + 256] = v1 * scale;
}

extern "C" void kernel_launch(void* const* d_in, const int* in_sizes, int n_in,
                              void* d_out, int out_size, void* d_ws, size_t ws_size,
                              hipStream_t stream) {
    const float* x       = (const float*)d_in[0];
    const float* conv_w  = (const float*)d_in[1];
    const float* conv_b  = (const float*)d_in[2];
    const float* centers = (const float*)d_in[3];
    float* out = (float*)d_out;

    char* wsb = (char*)d_ws;
    float* vlad = (float*)wsb;                                           // 2 MiB
    float* wbuf = (float*)(wsb + (size_t)B_ * K_ * D_ * sizeof(float));  // 16 MiB

    hipMemsetAsync(vlad, 0, (size_t)B_ * K_ * D_ * sizeof(float), stream);

    k_softmax<<<B_ * (N_ / 128), 256, 0, stream>>>(x, conv_w, conv_b, wbuf);
    k_wx<<<B_ * 8 * 4, 256, 0, stream>>>(x, wbuf, vlad);
    k_norm<<<B_ * K_, 256, 0, stream>>>(wbuf, vlad, centers, out);
}

// Round 3
// 237.624 us; speedup vs baseline: 3.2137x; 1.4125x over previous
//
#include <hip/hip_runtime.h>
#include <hip/hip_bf16.h>
#include <math.h>

#define B_ 16
#define D_ 512
#define N_ 4096   // H*W
#define K_ 64

typedef __attribute__((ext_vector_type(8))) short bfrag;   // 8 bf16 = 4 VGPRs
typedef __attribute__((ext_vector_type(4))) float f32x4;

static __device__ __forceinline__ float bf2f(unsigned short u) {
    return __uint_as_float(((unsigned)u) << 16);
}
static __device__ __forceinline__ unsigned short f2bf(float v) {
    __hip_bfloat16 h = __float2bfloat16(v);   // RNE
    union { __hip_bfloat16 h; unsigned short u; } cv; cv.h = h; return cv.u;
}
static __device__ __forceinline__ void split3(float v, unsigned short& h,
                                              unsigned short& m, unsigned short& l) {
    h = f2bf(v); float r1 = v - bf2f(h);
    m = f2bf(r1); float r2 = r1 - bf2f(m);
    l = f2bf(r2);
}
static __device__ __forceinline__ void split2(float v, unsigned short& h,
                                              unsigned short& l) {
    h = f2bf(v); l = f2bf(v - bf2f(h));
}
#define MFMA(a, b, c) __builtin_amdgcn_mfma_f32_16x16x32_bf16((a), (b), (c), 0, 0, 0)

// ---------------------------------------------------------------------------
// K1: logits = conv_w(64xD) . x(DxN) + b  via 3-way-split bf16 MFMA (6 products
// ~ 24-bit mantissa), then cross-wave softmax over k, emit w as bf16 hi/lo.
// Block: 64k x 128n, d-loop 16 steps of 32. Wave: 2 k-tiles x 4 n-tiles.
// ---------------------------------------------------------------------------
__global__ __launch_bounds__(256) void k_logits_softmax(
    const float* __restrict__ x, const float* __restrict__ conv_w,
    const float* __restrict__ conv_b,
    unsigned short* __restrict__ wh, unsigned short* __restrict__ wl)
{
    const int b   = blockIdx.x >> 5;
    const int n0  = (blockIdx.x & 31) * 128;
    const int tid  = threadIdx.x;
    const int w    = tid >> 6;
    const int lane = tid & 63;
    const int q = lane >> 4;
    const int c = lane & 15;
    const int ktb = (w & 1) * 32;    // waves 0,2: k 0-31; waves 1,3: k 32-63
    const int ntb = (w >> 1) * 64;   // waves 0,1: n 0-63; waves 2,3: n 64-127

    __shared__ unsigned short cws[3][64][40];   // [lvl][k][d], rows 80 B
    __shared__ unsigned short xs[3][128][40];   // [lvl][n][d]
    __shared__ float redm[2][128];
    __shared__ float reds[2][128];

    f32x4 acc[2][4];
    #pragma unroll
    for (int kt = 0; kt < 2; ++kt)
        #pragma unroll
        for (int nt = 0; nt < 4; ++nt) acc[kt][nt] = (f32x4){0.f, 0.f, 0.f, 0.f};

    const float* xb = x + (size_t)b * D_ * N_ + n0;

    for (int d0 = 0; d0 < D_; d0 += 32) {
        // stage conv_w 64k x 32d, 3-way split (float4 loads, coalesced on d)
        #pragma unroll
        for (int i = 0; i < 2; ++i) {
            const int s  = i * 256 + tid;
            const int k  = s >> 3;
            const int d4 = (s & 7) * 4;
            const float4 v = *(const float4*)&conv_w[k * D_ + d0 + d4];
            const float vv[4] = {v.x, v.y, v.z, v.w};
            unsigned short h[4], m[4], l[4];
            #pragma unroll
            for (int j = 0; j < 4; ++j) split3(vv[j], h[j], m[j], l[j]);
            *(ushort4*)&cws[0][k][d4] = make_ushort4(h[0], h[1], h[2], h[3]);
            *(ushort4*)&cws[1][k][d4] = make_ushort4(m[0], m[1], m[2], m[3]);
            *(ushort4*)&cws[2][k][d4] = make_ushort4(l[0], l[1], l[2], l[3]);
        }
        // stage x 32d x 128n transposed -> xs[n][d] (coalesced dword loads on n)
        #pragma unroll
        for (int i = 0; i < 4; ++i) {
            const int s  = i * 256 + tid;
            const int n  = s & 127;
            const int dg = (s >> 7) * 4;
            unsigned short h[4], m[4], l[4];
            #pragma unroll
            for (int r = 0; r < 4; ++r) {
                const float v = xb[(size_t)(d0 + dg + r) * N_ + n];
                split3(v, h[r], m[r], l[r]);
            }
            *(ushort4*)&xs[0][n][dg] = make_ushort4(h[0], h[1], h[2], h[3]);
            *(ushort4*)&xs[1][n][dg] = make_ushort4(m[0], m[1], m[2], m[3]);
            *(ushort4*)&xs[2][n][dg] = make_ushort4(l[0], l[1], l[2], l[3]);
        }
        __syncthreads();

        bfrag af[2][3];
        #pragma unroll
        for (int kt = 0; kt < 2; ++kt)
            #pragma unroll
            for (int lv = 0; lv < 3; ++lv)
                af[kt][lv] = *(const bfrag*)&cws[lv][ktb + kt * 16 + c][q * 8];
        #pragma unroll
        for (int nt = 0; nt < 4; ++nt) {
            bfrag bf[3];
            #pragma unroll
            for (int lv = 0; lv < 3; ++lv)
                bf[lv] = *(const bfrag*)&xs[lv][ntb + nt * 16 + c][q * 8];
            #pragma unroll
            for (int kt = 0; kt < 2; ++kt) {
                f32x4 a = acc[kt][nt];
                a = MFMA(af[kt][0], bf[0], a);   // hh
                a = MFMA(af[kt][0], bf[1], a);   // hm
                a = MFMA(af[kt][1], bf[0], a);   // mh
                a = MFMA(af[kt][1], bf[1], a);   // mm
                a = MFMA(af[kt][0], bf[2], a);   // hl
                a = MFMA(af[kt][2], bf[0], a);   // lh
                acc[kt][nt] = a;
            }
        }
        __syncthreads();
    }

    // ---- bias + cross-wave softmax over k (lane owns k=ktb+kt*16+q*4+r, n=ntb+nt*16+c)
    #pragma unroll
    for (int kt = 0; kt < 2; ++kt) {
        #pragma unroll
        for (int r = 0; r < 4; ++r) {
            const float bias = conv_b[ktb + kt * 16 + q * 4 + r];
            #pragma unroll
            for (int nt = 0; nt < 4; ++nt) acc[kt][nt][r] += bias;
        }
    }
    float mloc[4];
    #pragma unroll
    for (int nt = 0; nt < 4; ++nt) {
        float m = acc[0][nt][0];
        #pragma unroll
        for (int kt = 0; kt < 2; ++kt)
            #pragma unroll
            for (int r = 0; r < 4; ++r) m = fmaxf(m, acc[kt][nt][r]);
        m = fmaxf(m, __shfl_xor(m, 16));
        m = fmaxf(m, __shfl_xor(m, 32));
        mloc[nt] = m;
    }
    if (q == 0)
        #pragma unroll
        for (int nt = 0; nt < 4; ++nt) redm[w & 1][ntb + nt * 16 + c] = mloc[nt];
    __syncthreads();
    float mall[4];
    #pragma unroll
    for (int nt = 0; nt < 4; ++nt)
        mall[nt] = fmaxf(redm[0][ntb + nt * 16 + c], redm[1][ntb + nt * 16 + c]);

    float sloc[4] = {0.f, 0.f, 0.f, 0.f};
    #pragma unroll
    for (int nt = 0; nt < 4; ++nt) {
        #pragma unroll
        for (int kt = 0; kt < 2; ++kt)
            #pragma unroll
            for (int r = 0; r < 4; ++r) {
                const float e = __expf(acc[kt][nt][r] - mall[nt]);
                acc[kt][nt][r] = e;
                sloc[nt] += e;
            }
        sloc[nt] += __shfl_xor(sloc[nt], 16);
        sloc[nt] += __shfl_xor(sloc[nt], 32);
    }
    if (q == 0)
        #pragma unroll
        for (int nt = 0; nt < 4; ++nt) reds[w & 1][ntb + nt * 16 + c] = sloc[nt];
    __syncthreads();

    #pragma unroll
    for (int nt = 0; nt < 4; ++nt) {
        const float inv = 1.0f / (reds[0][ntb + nt * 16 + c] + reds[1][ntb + nt * 16 + c]);
        #pragma unroll
        for (int kt = 0; kt < 2; ++kt)
            #pragma unroll
            for (int r = 0; r < 4; ++r) {
                const float v = acc[kt][nt][r] * inv;
                unsigned short hi, lo;
                split2(v, hi, lo);
                const size_t idx = ((size_t)b * K_ + ktb + kt * 16 + q * 4 + r) * N_
                                 + n0 + ntb + nt * 16 + c;
                wh[idx] = hi;
                wl[idx] = lo;
            }
    }
}

// ---------------------------------------------------------------------------
// K2: vlad[b,k,d] += sum_n w[k,n]*x[d,n] via 2-way-split bf16 MFMA (3 products).
// Block: 64k x 128d, n-chunk 512 (8 chunks, atomicAdd). w limbs copied raw.
// ---------------------------------------------------------------------------
__global__ __launch_bounds__(256) void k_wx(
    const float* __restrict__ x, const unsigned short* __restrict__ wh,
    const unsigned short* __restrict__ wl, float* __restrict__ vlad)
{
    const int nc = blockIdx.x & 7;
    const int dc = (blockIdx.x >> 3) & 3;
    const int b  = blockIdx.x >> 5;
    const int tid  = threadIdx.x;
    const int w    = tid >> 6;
    const int lane = tid & 63;
    const int q = lane >> 4;
    const int c = lane & 15;
    const int ktb = (w & 1) * 32;
    const int dtb = (w >> 1) * 64;

    __shared__ unsigned short ws2[2][64][40];    // [lvl][k][n]
    __shared__ unsigned short xs2[2][128][40];   // [lvl][d][n]

    f32x4 acc[2][4];
    #pragma unroll
    for (int kt = 0; kt < 2; ++kt)
        #pragma unroll
        for (int dt = 0; dt < 4; ++dt) acc[kt][dt] = (f32x4){0.f, 0.f, 0.f, 0.f};

    const float* xb = x + (size_t)b * D_ * N_ + (size_t)dc * 128 * N_;
    const unsigned short* whb = wh + (size_t)b * K_ * N_;
    const unsigned short* wlb = wl + (size_t)b * K_ * N_;

    const int nbase = nc * 512;
    for (int n0 = nbase; n0 < nbase + 512; n0 += 32) {
        {   // stage w limbs: raw 16B copies, 64k x 32n each level
            const int k  = tid >> 2;
            const int ng = (tid & 3) * 8;
            *(uint4*)&ws2[0][k][ng] = *(const uint4*)&whb[(size_t)k * N_ + n0 + ng];
            *(uint4*)&ws2[1][k][ng] = *(const uint4*)&wlb[(size_t)k * N_ + n0 + ng];
        }
        // stage x 128d x 32n, 2-way split (float4 loads, coalesced on n)
        #pragma unroll
        for (int i = 0; i < 4; ++i) {
            const int s  = i * 256 + tid;
            const int d  = s >> 3;
            const int n4 = (s & 7) * 4;
            const float4 v = *(const float4*)&xb[(size_t)d * N_ + n0 + n4];
            const float vv[4] = {v.x, v.y, v.z, v.w};
            unsigned short h[4], l[4];
            #pragma unroll
            for (int j = 0; j < 4; ++j) split2(vv[j], h[j], l[j]);
            *(ushort4*)&xs2[0][d][n4] = make_ushort4(h[0], h[1], h[2], h[3]);
            *(ushort4*)&xs2[1][d][n4] = make_ushort4(l[0], l[1], l[2], l[3]);
        }
        __syncthreads();

        bfrag afh[2], afl[2];
        #pragma unroll
        for (int kt = 0; kt < 2; ++kt) {
            afh[kt] = *(const bfrag*)&ws2[0][ktb + kt * 16 + c][q * 8];
            afl[kt] = *(const bfrag*)&ws2[1][ktb + kt * 16 + c][q * 8];
        }
        #pragma unroll
        for (int dt = 0; dt < 4; ++dt) {
            const bfrag bh = *(const bfrag*)&xs2[0][dtb + dt * 16 + c][q * 8];
            const bfrag bl = *(const bfrag*)&xs2[1][dtb + dt * 16 + c][q * 8];
            #pragma unroll
            for (int kt = 0; kt < 2; ++kt) {
                f32x4 a = acc[kt][dt];
                a = MFMA(afh[kt], bh, a);
                a = MFMA(afh[kt], bl, a);
                a = MFMA(afl[kt], bh, a);
                acc[kt][dt] = a;
            }
        }
        __syncthreads();
    }

    #pragma unroll
    for (int kt = 0; kt < 2; ++kt)
        #pragma unroll
        for (int dt = 0; dt < 4; ++dt)
            #pragma unroll
            for (int r = 0; r < 4; ++r) {
                const int k = ktb + kt * 16 + q * 4 + r;
                const int d = dc * 128 + dtb + dt * 16 + c;
                atomicAdd(&vlad[((size_t)b * K_ + k) * D_ + d], acc[kt][dt][r]);
            }
}

// ---------------------------------------------------------------------------
// K3: wsum from w limbs; v = vlad - wsum*c; row L2-norm; global norm = /8.
// ---------------------------------------------------------------------------
__global__ __launch_bounds__(256) void k_norm(
    const unsigned short* __restrict__ wh, const unsigned short* __restrict__ wl,
    const float* __restrict__ vlad, const float* __restrict__ centers,
    float* __restrict__ out)
{
    const int b = blockIdx.x >> 6;
    const int k = blockIdx.x & 63;
    const int tid = threadIdx.x;

    const unsigned short* whr = wh + ((size_t)b * K_ + k) * N_;
    const unsigned short* wlr = wl + ((size_t)b * K_ + k) * N_;
    float s = 0.f;
    #pragma unroll
    for (int i = 0; i < 2; ++i) {
        const uint4 ah = *(const uint4*)&whr[(i * 256 + tid) * 8];
        const uint4 al = *(const uint4*)&wlr[(i * 256 + tid) * 8];
        const unsigned u[8] = {ah.x, ah.y, ah.z, ah.w, al.x, al.y, al.z, al.w};
        #pragma unroll
        for (int j = 0; j < 8; ++j) {
            s += __uint_as_float(u[j] << 16);
            s += __uint_as_float(u[j] & 0xffff0000u);
        }
    }
    __shared__ float red1[4];
    #pragma unroll
    for (int off = 32; off > 0; off >>= 1) s += __shfl_down(s, off, 64);
    if ((tid & 63) == 0) red1[tid >> 6] = s;
    __syncthreads();
    const float wsum = red1[0] + red1[1] + red1[2] + red1[3];

    const float* vr = vlad + ((size_t)b * K_ + k) * D_;
    const float* cr = centers + k * D_;
    const float v0 = vr[tid]       - wsum * cr[tid];
    const float v1 = vr[tid + 256] - wsum * cr[tid + 256];

    float ss = v0 * v0 + v1 * v1;
    __shared__ float red2[4];
    #pragma unroll
    for (int off = 32; off > 0; off >>= 1) ss += __shfl_down(ss, off, 64);
    if ((tid & 63) == 0) red2[tid >> 6] = ss;
    __syncthreads();
    const float nrm = sqrtf(red2[0] + red2[1] + red2[2] + red2[3]);
    const float scale = 1.0f / (8.0f * fmaxf(nrm, 1e-12f));

    float* outr = out + ((size_t)b * K_ + k) * D_;
    outr[tid]       = v0 * scale;
    outr[tid + 256] = v1 * scale;
}

extern "C" void kernel_launch(void* const* d_in, const int* in_sizes, int n_in,
                              void* d_out, int out_size, void* d_ws, size_t ws_size,
                              hipStream_t stream) {
    const float* x       = (const float*)d_in[0];
    const float* conv_w  = (const float*)d_in[1];
    const float* conv_b  = (const float*)d_in[2];
    const float* centers = (const float*)d_in[3];
    float* out = (float*)d_out;

    char* wsb = (char*)d_ws;
    float* vlad = (float*)wsb;                                        // 2 MiB
    unsigned short* wh = (unsigned short*)(wsb + (2u << 20));         // 8 MiB
    unsigned short* wl = (unsigned short*)(wsb + (10u << 20));        // 8 MiB

    hipMemsetAsync(vlad, 0, (size_t)B_ * K_ * D_ * sizeof(float), stream);

    k_logits_softmax<<<B_ * 32, 256, 0, stream>>>(x, conv_w, conv_b, wh, wl);
    k_wx<<<B_ * 4 * 8, 256, 0, stream>>>(x, wh, wl, vlad);
    k_norm<<<B_ * K_, 256, 0, stream>>>(wh, wl, vlad, centers, out);
}